// Round 1
// baseline (1308.035 us; speedup 1.0000x reference)
//
#include <hip/hip_runtime.h>
#include <math.h>

namespace {
constexpr int B_ = 128;
constexpr int N_ = 256;
constexpr int C_ = 4;
constexpr int IN_ = 64;
constexpr int H_ = 128;
constexpr int G_ = 8;
constexpr int M_TOTAL = B_ * N_;  // 32768 nodes
}

// Fourier-KAN linear: out[node][o] = sum_{i,g} cos(x[node][i]*(g+1))*W[0][o][i][g]
//                                  + sin(x[node][i]*(g+1))*W[1][o][i][g]
// GEMM view: M=nodes, N=128, K=IN*G*2. Block: 64 nodes x 128 outs, 256 threads.
template<int IN>
__global__ __launch_bounds__(256)
void fourier_kernel(const float* __restrict__ x,   // [M][IN]
                    const float* __restrict__ W,   // [2][128][IN][8]
                    float* __restrict__ out)       // [M][128]
{
  constexpr int PAIRS = IN * G_;       // 512 or 1024
  constexpr int CHUNKS = PAIRS / 32;   // 16 or 32 (4 inputs per chunk)
  __shared__ float featC[32][64];      // [pair-in-chunk][node]
  __shared__ float featS[32][64];
  __shared__ float wlds[2][32][128];   // [sin/cos][pair-in-chunk][out]

  const int tid = threadIdx.x;
  const int node0 = blockIdx.x * 64;

  const int og = tid & 15;    // out group: outputs og*4..+3 and og*4+64..+67
  const int ng = tid >> 4;    // node group: nodes ng*4..+3
  const int nd_f = tid & 63;  // feature staging: node
  const int il_f = tid >> 6;  // feature staging: input-within-chunk 0..3
  const int s_w = tid >> 7;   // weight staging: trig index
  const int o_w = tid & 127;  // weight staging: output row

  float acc[4][8];
  #pragma unroll
  for (int a = 0; a < 4; ++a)
    #pragma unroll
    for (int b = 0; b < 8; ++b) acc[a][b] = 0.f;

  const float* wrow = W + (size_t)(s_w * H_ + o_w) * PAIRS;
  const float* xrow = x + (size_t)(node0 + nd_f) * IN;

  for (int ic = 0; ic < CHUNKS; ++ic) {
    __syncthreads();
    // --- stage weights: thread (s_w, o_w) copies 32 consecutive K-elems of its row
    #pragma unroll
    for (int j4 = 0; j4 < 8; ++j4) {
      float4 v = *(const float4*)(wrow + ic * 32 + j4 * 4);
      wlds[s_w][j4 * 4 + 0][o_w] = v.x;
      wlds[s_w][j4 * 4 + 1][o_w] = v.y;
      wlds[s_w][j4 * 4 + 2][o_w] = v.z;
      wlds[s_w][j4 * 4 + 3][o_w] = v.w;
    }
    // --- stage features: one sincos + Chebyshev recurrence for k=1..8
    {
      float xv = xrow[ic * 4 + il_f];
      float c1 = cosf(xv), s1 = sinf(xv);
      float ckm = 1.f, skm = 0.f;   // k=0
      float ck = c1, sk = s1;       // k=1
      #pragma unroll
      for (int g = 0; g < 8; ++g) {
        featC[il_f * 8 + g][nd_f] = ck;
        featS[il_f * 8 + g][nd_f] = sk;
        float cn = 2.f * c1 * ck - ckm;
        float sn = 2.f * c1 * sk - skm;
        ckm = ck; skm = sk; ck = cn; sk = sn;
      }
    }
    __syncthreads();
    // --- inner: 32 pairs x (4 nodes x 8 outs x {cos,sin})
    #pragma unroll 4
    for (int j = 0; j < 32; ++j) {
      float4 fc = *(const float4*)&featC[j][ng * 4];
      float4 fs = *(const float4*)&featS[j][ng * 4];
      float4 w0a = *(const float4*)&wlds[0][j][og * 4];
      float4 w0b = *(const float4*)&wlds[0][j][og * 4 + 64];
      float4 w1a = *(const float4*)&wlds[1][j][og * 4];
      float4 w1b = *(const float4*)&wlds[1][j][og * 4 + 64];
      float fcv[4] = {fc.x, fc.y, fc.z, fc.w};
      float fsv[4] = {fs.x, fs.y, fs.z, fs.w};
      float wa0[4] = {w0a.x, w0a.y, w0a.z, w0a.w};
      float wb0[4] = {w0b.x, w0b.y, w0b.z, w0b.w};
      float wa1[4] = {w1a.x, w1a.y, w1a.z, w1a.w};
      float wb1[4] = {w1b.x, w1b.y, w1b.z, w1b.w};
      #pragma unroll
      for (int nd = 0; nd < 4; ++nd) {
        #pragma unroll
        for (int oo = 0; oo < 4; ++oo) {
          acc[nd][oo]     += fcv[nd] * wa0[oo] + fsv[nd] * wa1[oo];
          acc[nd][4 + oo] += fcv[nd] * wb0[oo] + fsv[nd] * wb1[oo];
        }
      }
    }
  }
  #pragma unroll
  for (int nd = 0; nd < 4; ++nd) {
    int row = node0 + ng * 4 + nd;
    float4 ra = {acc[nd][0], acc[nd][1], acc[nd][2], acc[nd][3]};
    float4 rb = {acc[nd][4], acc[nd][5], acc[nd][6], acc[nd][7]};
    *(float4*)&out[(size_t)row * H_ + og * 4] = ra;
    *(float4*)&out[(size_t)row * H_ + og * 4 + 64] = rb;
  }
}

// Aggregation + residual + leaky_relu:
//   h_out[b][m][o] = leaky( sum_{k=0..1023} A[b][k/4][k%4][m] * f[b][k/4][o] + h_in[b][m][o] )
// A's (n,c,m) flattens so A[b][n][c][m] = Ab[k*256 + m] with k = n*4+c.
__global__ __launch_bounds__(256)
void agg_kernel(const float* __restrict__ A,     // [B][N][C][N]
                const float* __restrict__ f,     // [B][N][128]
                const float* __restrict__ h_in,  // [B][N][128]
                float* __restrict__ h_out)       // [B][N][128]
{
  __shared__ float As[16][128];   // [k-in-chunk][m]
  __shared__ float fsh[4][128];   // [n-in-chunk][o]
  const int tid = threadIdx.x;
  const int b = blockIdx.x >> 1;
  const int mh = blockIdx.x & 1;
  const int m0 = mh * 128;

  const int og = tid & 15;  // outputs og*4..+3 and og*4+64..+67
  const int mg = tid >> 4;  // rows mg*8..+7

  float acc[8][8];
  #pragma unroll
  for (int i = 0; i < 8; ++i)
    #pragma unroll
    for (int j = 0; j < 8; ++j) acc[i][j] = 0.f;

  const float* Ab = A + (size_t)b * N_ * C_ * N_;
  const float* fb = f + (size_t)b * N_ * H_;

  for (int ch = 0; ch < 64; ++ch) {   // K=1024, chunk 16
    __syncthreads();
    #pragma unroll
    for (int t = 0; t < 8; ++t) {
      int idx = tid + t * 256;
      int kk = idx >> 7;
      int mm = idx & 127;
      As[kk][mm] = Ab[(size_t)(ch * 16 + kk) * N_ + m0 + mm];
    }
    #pragma unroll
    for (int t = 0; t < 2; ++t) {
      int idx = tid + t * 256;
      int nn = idx >> 7;
      int o = idx & 127;
      fsh[nn][o] = fb[(size_t)(ch * 4 + nn) * H_ + o];
    }
    __syncthreads();
    #pragma unroll 4
    for (int kk = 0; kk < 16; ++kk) {
      float4 a0 = *(const float4*)&As[kk][mg * 8];
      float4 a1 = *(const float4*)&As[kk][mg * 8 + 4];
      float4 f0 = *(const float4*)&fsh[kk >> 2][og * 4];
      float4 f1 = *(const float4*)&fsh[kk >> 2][og * 4 + 64];
      float am[8] = {a0.x, a0.y, a0.z, a0.w, a1.x, a1.y, a1.z, a1.w};
      float fo[8] = {f0.x, f0.y, f0.z, f0.w, f1.x, f1.y, f1.z, f1.w};
      #pragma unroll
      for (int mi = 0; mi < 8; ++mi)
        #pragma unroll
        for (int oi = 0; oi < 8; ++oi)
          acc[mi][oi] += am[mi] * fo[oi];
    }
  }
  #pragma unroll
  for (int mi = 0; mi < 8; ++mi) {
    int row = b * N_ + m0 + mg * 8 + mi;
    const float* hr = &h_in[(size_t)row * H_];
    float* ho = &h_out[(size_t)row * H_];
    float4 r0 = *(const float4*)&hr[og * 4];
    float4 r1 = *(const float4*)&hr[og * 4 + 64];
    float4 o0, o1;
    float v;
    v = acc[mi][0] + r0.x; o0.x = v >= 0.f ? v : 0.01f * v;
    v = acc[mi][1] + r0.y; o0.y = v >= 0.f ? v : 0.01f * v;
    v = acc[mi][2] + r0.z; o0.z = v >= 0.f ? v : 0.01f * v;
    v = acc[mi][3] + r0.w; o0.w = v >= 0.f ? v : 0.01f * v;
    v = acc[mi][4] + r1.x; o1.x = v >= 0.f ? v : 0.01f * v;
    v = acc[mi][5] + r1.y; o1.y = v >= 0.f ? v : 0.01f * v;
    v = acc[mi][6] + r1.z; o1.z = v >= 0.f ? v : 0.01f * v;
    v = acc[mi][7] + r1.w; o1.w = v >= 0.f ? v : 0.01f * v;
    *(float4*)&ho[og * 4] = o0;
    *(float4*)&ho[og * 4 + 64] = o1;
  }
}

// Masked mean pool over first mol_size nodes, then KAN head (grid=1) + sigmoid.
__global__ __launch_bounds__(128)
void pool_kernel(const float* __restrict__ h,     // [B][N][128]
                 const int* __restrict__ mol,     // [B]
                 const float* __restrict__ Wout,  // [2][1][128][1]
                 const float* __restrict__ bout,  // [1][1]
                 float* __restrict__ out)         // [B]
{
  __shared__ float red[128];
  const int b = blockIdx.x;
  const int t = threadIdx.x;
  const int ms = mol[b];
  const float* hb = h + (size_t)b * N_ * H_;
  float sum = 0.f;
  for (int n = 0; n < ms; ++n) sum += hb[(size_t)n * H_ + t];
  float y = sum / (float)ms;
  float v = cosf(y) * Wout[t] + sinf(y) * Wout[H_ + t];
  red[t] = v;
  __syncthreads();
  for (int sft = 64; sft > 0; sft >>= 1) {
    if (t < sft) red[t] += red[t + sft];
    __syncthreads();
  }
  if (t == 0) {
    float z = red[0] + bout[0];
    out[b] = 1.f / (1.f + expf(-z));
  }
}

extern "C" void kernel_launch(void* const* d_in, const int* in_sizes, int n_in,
                              void* d_out, int out_size, void* d_ws, size_t ws_size,
                              hipStream_t stream) {
  const float* V    = (const float*)d_in[0];
  const float* A    = (const float*)d_in[1];
  const int*   mol  = (const int*)d_in[2];
  const float* Win  = (const float*)d_in[3];
  const float* Wg   = (const float*)d_in[4];
  const float* Wout = (const float*)d_in[5];
  const float* bout = (const float*)d_in[6];
  float* out = (float*)d_out;

  float* h  = (float*)d_ws;                      // [32768][128]
  float* f  = h + (size_t)M_TOTAL * H_;          // [32768][128]
  float* h2 = f + (size_t)M_TOTAL * H_;          // [32768][128]

  fourier_kernel<IN_><<<M_TOTAL / 64, 256, 0, stream>>>(V, Win, h);

  float* hc = h;
  float* hn = h2;
  for (int l = 0; l < 2; ++l) {
    fourier_kernel<H_><<<M_TOTAL / 64, 256, 0, stream>>>(
        hc, Wg + (size_t)l * 2 * H_ * H_ * G_, f);
    agg_kernel<<<B_ * 2, 256, 0, stream>>>(A, f, hc, hn);
    float* tmp = hc; hc = hn; hn = tmp;
  }

  pool_kernel<<<B_, 128, 0, stream>>>(hc, mol, Wout, bout, out);
}